// Round 11
// baseline (178.033 us; speedup 1.0000x reference)
//
#include <hip/hip_runtime.h>
#include <hip/hip_bf16.h>

#define EPS 1e-5f

// ---- workspace layout (float offsets) ----
#define OFF_ABAR 0          // 128*64*72   = 589824 floats
#define OFF_U    589824     // 128*64*256  = 2097152
#define OFF_V    2686976    // 2097152
#define OFF_PART 4784128    // 2048*256    = 524288  -> total 5308416 fl = 21.2 MB

__device__ __forceinline__ float elu(float z) {
    return z > 0.f ? z : __expf(z) - 1.f;
}

// DPP all-reduce over each 16-lane row: 4 full-rate VALU adds, no LDS pipe.
// dpp_ctrl must be a compile-time constant -> template parameter.
template <int CTRL>
__device__ __forceinline__ float dpp_add(float x) {
    int y = __builtin_amdgcn_update_dpp(0, __float_as_int(x), CTRL, 0xf, 0xf, true);
    return x + __int_as_float(y);
}
__device__ __forceinline__ float allred16(float x) {
    x = dpp_add<0x121>(x);  // row_ror:1
    x = dpp_add<0x122>(x);  // row_ror:2
    x = dpp_add<0x124>(x);  // row_ror:4
    x = dpp_add<0x128>(x);  // row_ror:8
    return x;
}

// K1: fused split-embedding + LayerNorm over (N,E) per batch.
__global__ __launch_bounds__(256) void k_embed_ln0(
    const float* __restrict__ xa, const float* __restrict__ xb,
    const float* __restrict__ Wa, const float* __restrict__ ba,
    const float* __restrict__ Wb, const float* __restrict__ bb,
    const float* __restrict__ g0, const float* __restrict__ b0,
    float* __restrict__ abar) {
    int b = blockIdx.x;
    int tid = threadIdx.x;
    float vals[18];
    float s1 = 0.f, s2 = 0.f;
    for (int m = 0; m < 18; ++m) {
        int k = tid + 256 * m;
        int e = k % 72;
        int n = k / 72;
        float acc;
        if (n < 32) {
            acc = ba[e];
            const float* x = xa + (b * 32 + n) * 23;
            #pragma unroll
            for (int d = 0; d < 23; ++d) acc = fmaf(x[d], Wa[d * 72 + e], acc);
        } else {
            acc = bb[e];
            const float* x = xb + (b * 32 + (n - 32)) * 13;
            #pragma unroll
            for (int d = 0; d < 13; ++d) acc = fmaf(x[d], Wb[d * 72 + e], acc);
        }
        vals[m] = acc;
        s1 += acc;
        s2 = fmaf(acc, acc, s2);
    }
    #pragma unroll
    for (int off = 32; off >= 1; off >>= 1) {
        s1 += __shfl_xor(s1, off, 64);
        s2 += __shfl_xor(s2, off, 64);
    }
    __shared__ float r1[4], r2[4];
    int w = tid >> 6;
    if ((tid & 63) == 0) { r1[w] = s1; r2[w] = s2; }
    __syncthreads();
    float t1 = r1[0] + r1[1] + r1[2] + r1[3];
    float t2 = r2[0] + r2[1] + r2[2] + r2[3];
    float mean = t1 * (1.f / 4608.f);
    float var  = fmaf(-mean, mean, t2 * (1.f / 4608.f));
    float rsq  = rsqrtf(var + EPS);
    float* ab = abar + b * 4608;
    for (int m = 0; m < 18; ++m) {
        int k = tid + 256 * m;
        ab[k] = fmaf((vals[m] - mean) * rsq, g0[k], b0[k]);
    }
}

// K2: U = abar @ Wg[0:72,:] (+ b_g folded in), V = abar @ Wg[72:144,:].
// grid = 1024 (128 b × 8 n-octets), block = 256 (thread = one h column).
__global__ __launch_bounds__(256) void k_uv(
    const float* __restrict__ abar, const float* __restrict__ Wg,
    const float* __restrict__ bg,
    float* __restrict__ U, float* __restrict__ V) {
    int blk = blockIdx.x;            // 1024 blocks
    int b = blk >> 3;
    int q = blk & 7;                 // n-range [q*8, q*8+8)
    int h = threadIdx.x;
    __shared__ float sa[72 * 8];     // [e][n], 2.25 KB
    const float* src = abar + (b * 64 + q * 8) * 72;
    for (int k = threadIdx.x; k < 72 * 8; k += 256) {
        int e = k >> 3, n = k & 7;
        sa[k] = src[n * 72 + e];
    }
    __syncthreads();
    float u[8], v[8];
    #pragma unroll
    for (int n = 0; n < 8; ++n) { u[n] = 0.f; v[n] = 0.f; }
    for (int e = 0; e < 72; ++e) {
        float wu = Wg[e * 256 + h];
        float wv = Wg[(72 + e) * 256 + h];
        const float4* sp = (const float4*)&sa[e * 8];
        #pragma unroll
        for (int n4 = 0; n4 < 2; ++n4) {
            float4 s4 = sp[n4];
            u[n4*4+0] = fmaf(s4.x, wu, u[n4*4+0]); v[n4*4+0] = fmaf(s4.x, wv, v[n4*4+0]);
            u[n4*4+1] = fmaf(s4.y, wu, u[n4*4+1]); v[n4*4+1] = fmaf(s4.y, wv, v[n4*4+1]);
            u[n4*4+2] = fmaf(s4.z, wu, u[n4*4+2]); v[n4*4+2] = fmaf(s4.z, wv, v[n4*4+2]);
            u[n4*4+3] = fmaf(s4.w, wu, u[n4*4+3]); v[n4*4+3] = fmaf(s4.w, wv, v[n4*4+3]);
        }
    }
    float bgh = bg[h];
    int base = (b * 64 + q * 8) * 256 + h;
    #pragma unroll
    for (int n = 0; n < 8; ++n) {
        U[base + n * 256] = u[n] + bgh;   // b_g folded into U
        V[base + n * 256] = v[n];
    }
}

// K3 v8: elu once, 16 h/thread (best per-elem instr count), DPP stats reduce.
// grid = 2048 (128 b × 4 iq × 4 jq); block = 256 threads (16 j × 16 hc).
// Thread (j16 = t>>4, hc = t&15) owns column j = jq*16 + j16 and 16 h's
// (h = hc*4 + 64c + k, c<4, k<4). V-slice in regs; U[b, iq*16..+16) in LDS.
// Per i: e[16] once; s1/s2 all-reduced over the 16-lane h-group with 4 DPP
// row_ror adds each (full-rate VALU, no DS); mu/rsq per-lane; acc += e*rsq;
// -mr folded per-thread. Cross-j: single LDS transpose pass (reuses Us).
// launch_bounds(256,6): 85-reg cap, natural use ~60 -> no spill.
__global__ __launch_bounds__(256, 6) void k_pair(
    const float* __restrict__ U, const float* __restrict__ V,
    float* __restrict__ part) {
    int blk = blockIdx.x;
    int b  = blk >> 4;
    int iq = (blk >> 2) & 3;
    int jq = blk & 3;
    int t  = threadIdx.x;
    int j16 = t >> 4;             // 0..15
    int hc  = t & 15;             // 0..15

    __shared__ float Us[16 * 256];   // 16 KB: U tile, then cross-j scratch

    // stage U[b, iq*16 .. +16) — coalesced float4 (4096 floats)
    const float* Ug = U + (size_t)(b * 64 + iq * 16) * 256;
    #pragma unroll
    for (int r = 0; r < 4; ++r) {
        int k = t * 4 + r * 1024;
        *(float4*)&Us[k] = *(const float4*)&Ug[k];
    }

    // V-slice into registers (16 consecutive lanes read dense rows)
    const float* Vrow = V + (size_t)(b * 64 + jq * 16 + j16) * 256;
    float v[16];
    #pragma unroll
    for (int c = 0; c < 4; ++c) {
        float4 v4 = *(const float4*)&Vrow[hc * 4 + 64 * c];
        v[c*4+0] = v4.x; v[c*4+1] = v4.y; v[c*4+2] = v4.z; v[c*4+3] = v4.w;
    }

    __syncthreads();

    float acc[16];
    #pragma unroll
    for (int k = 0; k < 16; ++k) acc[k] = 0.f;
    float macc = 0.f;

    for (int i = 0; i < 16; ++i) {
        const float* ur = &Us[i * 256];
        float e[16];
        float s1 = 0.f, s2 = 0.f;
        #pragma unroll
        for (int c = 0; c < 4; ++c) {
            float4 u4 = *(const float4*)&ur[hc * 4 + 64 * c];
            float e0 = elu(u4.x + v[c*4+0]);
            float e1 = elu(u4.y + v[c*4+1]);
            float e2 = elu(u4.z + v[c*4+2]);
            float e3 = elu(u4.w + v[c*4+3]);
            e[c*4+0] = e0; e[c*4+1] = e1; e[c*4+2] = e2; e[c*4+3] = e3;
            s1 += (e0 + e1) + (e2 + e3);
            s2 = fmaf(e0, e0, fmaf(e1, e1, fmaf(e2, e2, fmaf(e3, e3, s2))));
        }
        // all-reduce over the 16-lane h-group — pure VALU DPP
        s1 = allred16(s1);
        s2 = allred16(s2);
        float mu  = s1 * (1.f / 256.f);
        float var = fmaf(-mu, mu, s2 * (1.f / 256.f));
        float rsq = rsqrtf(var + EPS);
        macc += mu * rsq;
        #pragma unroll
        for (int k = 0; k < 16; ++k) acc[k] = fmaf(e[k], rsq, acc[k]);
    }
    #pragma unroll
    for (int k = 0; k < 16; ++k) acc[k] -= macc;

    // cross-j reduce via LDS transpose (Us reusable after barrier)
    __syncthreads();
    #pragma unroll
    for (int c = 0; c < 4; ++c)
        *(float4*)&Us[j16 * 256 + hc * 4 + 64 * c] =
            make_float4(acc[c*4+0], acc[c*4+1], acc[c*4+2], acc[c*4+3]);
    __syncthreads();
    float r = 0.f;
    #pragma unroll
    for (int q = 0; q < 16; ++q) r += Us[q * 256 + t];
    part[(size_t)blk * 256 + t] = r;
}

// K4: reduce 16 partials, apply lng_g / (4096 * lng_b), 256x128 GEMM + elu.
__global__ __launch_bounds__(256) void k_out(
    const float* __restrict__ part,
    const float* __restrict__ lgg, const float* __restrict__ lgb,
    const float* __restrict__ Wf,  const float* __restrict__ bfb,
    float* __restrict__ out) {
    int b = blockIdx.x;
    int t = threadIdx.x;  // 256
    __shared__ float sh[256];
    __shared__ float ps[256];
    {
        float s = 0.f;
        #pragma unroll
        for (int p = 0; p < 16; ++p) s += part[(size_t)(b * 16 + p) * 256 + t];
        sh[t] = fmaf(lgg[t], s, 4096.f * lgb[t]);
    }
    __syncthreads();
    int f = t & 127, half = t >> 7;
    float acc = 0.f;
    for (int h = half * 128; h < half * 128 + 128; ++h)
        acc = fmaf(sh[h], Wf[h * 128 + f], acc);
    ps[t] = acc;
    __syncthreads();
    if (t < 128) {
        float r = ps[t] + ps[t + 128] + bfb[t];
        out[b * 128 + t] = r > 0.f ? r : __expf(r) - 1.f;
    }
}

extern "C" void kernel_launch(void* const* d_in, const int* in_sizes, int n_in,
                              void* d_out, int out_size, void* d_ws, size_t ws_size,
                              hipStream_t stream) {
    const float* xa  = (const float*)d_in[0];
    const float* xb  = (const float*)d_in[1];
    const float* Wa  = (const float*)d_in[2];
    const float* ba  = (const float*)d_in[3];
    const float* Wb  = (const float*)d_in[4];
    const float* bb  = (const float*)d_in[5];
    const float* g0  = (const float*)d_in[6];
    const float* b0  = (const float*)d_in[7];
    const float* Wg  = (const float*)d_in[8];
    const float* bg  = (const float*)d_in[9];
    const float* lgg = (const float*)d_in[10];
    const float* lgb = (const float*)d_in[11];
    const float* Wf  = (const float*)d_in[12];
    const float* bfb = (const float*)d_in[13];
    float* out = (float*)d_out;

    float* ws   = (float*)d_ws;
    float* abar = ws + OFF_ABAR;
    float* U    = ws + OFF_U;
    float* V    = ws + OFF_V;
    float* part = ws + OFF_PART;

    k_embed_ln0<<<128, 256, 0, stream>>>(xa, xb, Wa, ba, Wb, bb, g0, b0, abar);
    k_uv<<<1024, 256, 0, stream>>>(abar, Wg, bg, U, V);
    k_pair<<<2048, 256, 0, stream>>>(U, V, part);
    k_out<<<128, 256, 0, stream>>>(part, lgg, lgb, Wf, bfb, out);
}

// Round 12
// 154.973 us; speedup vs baseline: 1.1488x; 1.1488x over previous
//
#include <hip/hip_runtime.h>
#include <hip/hip_bf16.h>

#define EPS 1e-5f

// ---- workspace layout (float offsets) ----
#define OFF_ABAR 0          // 128*64*72   = 589824 floats
#define OFF_U    589824     // 128*64*256  = 2097152
#define OFF_V    2686976    // 2097152
#define OFF_PART 4784128    // 4096*256    = 1048576 -> total 5832704 fl = 23.3 MB

__device__ __forceinline__ float elu(float z) {
    return z > 0.f ? z : __expf(z) - 1.f;
}

// K1: fused split-embedding + LayerNorm over (N,E) per batch.
__global__ __launch_bounds__(256) void k_embed_ln0(
    const float* __restrict__ xa, const float* __restrict__ xb,
    const float* __restrict__ Wa, const float* __restrict__ ba,
    const float* __restrict__ Wb, const float* __restrict__ bb,
    const float* __restrict__ g0, const float* __restrict__ b0,
    float* __restrict__ abar) {
    int b = blockIdx.x;
    int tid = threadIdx.x;
    float vals[18];
    float s1 = 0.f, s2 = 0.f;
    for (int m = 0; m < 18; ++m) {
        int k = tid + 256 * m;
        int e = k % 72;
        int n = k / 72;
        float acc;
        if (n < 32) {
            acc = ba[e];
            const float* x = xa + (b * 32 + n) * 23;
            #pragma unroll
            for (int d = 0; d < 23; ++d) acc = fmaf(x[d], Wa[d * 72 + e], acc);
        } else {
            acc = bb[e];
            const float* x = xb + (b * 32 + (n - 32)) * 13;
            #pragma unroll
            for (int d = 0; d < 13; ++d) acc = fmaf(x[d], Wb[d * 72 + e], acc);
        }
        vals[m] = acc;
        s1 += acc;
        s2 = fmaf(acc, acc, s2);
    }
    #pragma unroll
    for (int off = 32; off >= 1; off >>= 1) {
        s1 += __shfl_xor(s1, off, 64);
        s2 += __shfl_xor(s2, off, 64);
    }
    __shared__ float r1[4], r2[4];
    int w = tid >> 6;
    if ((tid & 63) == 0) { r1[w] = s1; r2[w] = s2; }
    __syncthreads();
    float t1 = r1[0] + r1[1] + r1[2] + r1[3];
    float t2 = r2[0] + r2[1] + r2[2] + r2[3];
    float mean = t1 * (1.f / 4608.f);
    float var  = fmaf(-mean, mean, t2 * (1.f / 4608.f));
    float rsq  = rsqrtf(var + EPS);
    float* ab = abar + b * 4608;
    for (int m = 0; m < 18; ++m) {
        int k = tid + 256 * m;
        ab[k] = fmaf((vals[m] - mean) * rsq, g0[k], b0[k]);
    }
}

// K2: U = abar @ Wg[0:72,:] (+ b_g folded in), V = abar @ Wg[72:144,:].
// R7-exact version: grid = 512 (128 b × 4 n-quarters), block = 256.
__global__ __launch_bounds__(256) void k_uv(
    const float* __restrict__ abar, const float* __restrict__ Wg,
    const float* __restrict__ bg,
    float* __restrict__ U, float* __restrict__ V) {
    int blk = blockIdx.x;            // 512 blocks
    int b = blk >> 2;
    int q = blk & 3;                 // n-range [q*16, q*16+16)
    int h = threadIdx.x;
    __shared__ float sa[72 * 16];    // [e][n], 4.5 KB
    const float* src = abar + (b * 64 + q * 16) * 72;
    for (int k = threadIdx.x; k < 72 * 16; k += 256) {
        int e = k >> 4, n = k & 15;
        sa[k] = src[n * 72 + e];
    }
    __syncthreads();
    float u[16], v[16];
    #pragma unroll
    for (int n = 0; n < 16; ++n) { u[n] = 0.f; v[n] = 0.f; }
    for (int e = 0; e < 72; ++e) {
        float wu = Wg[e * 256 + h];
        float wv = Wg[(72 + e) * 256 + h];
        const float4* sp = (const float4*)&sa[e * 16];
        #pragma unroll
        for (int n4 = 0; n4 < 4; ++n4) {
            float4 s4 = sp[n4];
            u[n4*4+0] = fmaf(s4.x, wu, u[n4*4+0]); v[n4*4+0] = fmaf(s4.x, wv, v[n4*4+0]);
            u[n4*4+1] = fmaf(s4.y, wu, u[n4*4+1]); v[n4*4+1] = fmaf(s4.y, wv, v[n4*4+1]);
            u[n4*4+2] = fmaf(s4.z, wu, u[n4*4+2]); v[n4*4+2] = fmaf(s4.z, wv, v[n4*4+2]);
            u[n4*4+3] = fmaf(s4.w, wu, u[n4*4+3]); v[n4*4+3] = fmaf(s4.w, wv, v[n4*4+3]);
        }
    }
    float bgh = bg[h];
    int base = (b * 64 + q * 16) * 256 + h;
    #pragma unroll
    for (int n = 0; n < 16; ++n) {
        U[base + n * 256] = u[n] + bgh;   // b_g folded into U
        V[base + n * 256] = v[n];
    }
}

// K3 v9: elu once, 16 h/thread, shfl stats reduce; 8-i blocks so the grid
// (4096) oversubscribes the 6-blocks/CU residency cap ~2.7x -> pipelined
// occupancy instead of one machine-fill + tail.
// grid = 4096 (128 b × 8 iq × 4 jq); block = 256 threads (16 j × 16 hc).
// Thread (j16 = t>>4, hc = t&15) owns column j = jq*16 + j16 and 16 h's
// (h = hc*4 + 64c + k). V-slice in regs; U[b, iq*8..+8) staged in 8 KB LDS.
// Per i: e[16] once; s1/s2 via 4 shfl_xor over the 16-lane h-group (DS pipe,
// overlaps other waves' VALU); mu/rsq per-lane; acc[16] += e*rsq; -mr folded
// per-thread. Cross-j: LDS transpose pass (16 KB scratch).
__global__ __launch_bounds__(256, 6) void k_pair(
    const float* __restrict__ U, const float* __restrict__ V,
    float* __restrict__ part) {
    int blk = blockIdx.x;
    int b  = blk >> 5;
    int iq = (blk >> 2) & 7;
    int jq = blk & 3;
    int t  = threadIdx.x;
    int j16 = t >> 4;             // 0..15
    int hc  = t & 15;             // 0..15

    __shared__ float Us[16 * 256];   // 16 KB: rows 0..7 = U tile; all = scratch

    // stage U[b, iq*8 .. +8) — coalesced float4 (2048 floats)
    const float* Ug = U + (size_t)(b * 64 + iq * 8) * 256;
    #pragma unroll
    for (int r = 0; r < 2; ++r) {
        int k = t * 4 + r * 1024;
        *(float4*)&Us[k] = *(const float4*)&Ug[k];
    }

    // V-slice into registers (16 consecutive lanes read dense rows)
    const float* Vrow = V + (size_t)(b * 64 + jq * 16 + j16) * 256;
    float v[16];
    #pragma unroll
    for (int c = 0; c < 4; ++c) {
        float4 v4 = *(const float4*)&Vrow[hc * 4 + 64 * c];
        v[c*4+0] = v4.x; v[c*4+1] = v4.y; v[c*4+2] = v4.z; v[c*4+3] = v4.w;
    }

    __syncthreads();

    float acc[16];
    #pragma unroll
    for (int k = 0; k < 16; ++k) acc[k] = 0.f;
    float macc = 0.f;

    for (int i = 0; i < 8; ++i) {
        const float* ur = &Us[i * 256];
        float e[16];
        float s1 = 0.f, s2 = 0.f;
        #pragma unroll
        for (int c = 0; c < 4; ++c) {
            float4 u4 = *(const float4*)&ur[hc * 4 + 64 * c];
            float e0 = elu(u4.x + v[c*4+0]);
            float e1 = elu(u4.y + v[c*4+1]);
            float e2 = elu(u4.z + v[c*4+2]);
            float e3 = elu(u4.w + v[c*4+3]);
            e[c*4+0] = e0; e[c*4+1] = e1; e[c*4+2] = e2; e[c*4+3] = e3;
            s1 += (e0 + e1) + (e2 + e3);
            s2 = fmaf(e0, e0, fmaf(e1, e1, fmaf(e2, e2, fmaf(e3, e3, s2))));
        }
        // reduce over the 16-lane h-group (same j) — DS pipe
        #pragma unroll
        for (int d = 1; d <= 8; d <<= 1) {
            s1 += __shfl_xor(s1, d, 64);
            s2 += __shfl_xor(s2, d, 64);
        }
        float mu  = s1 * (1.f / 256.f);
        float var = fmaf(-mu, mu, s2 * (1.f / 256.f));
        float rsq = rsqrtf(var + EPS);
        macc += mu * rsq;
        #pragma unroll
        for (int k = 0; k < 16; ++k) acc[k] = fmaf(e[k], rsq, acc[k]);
    }
    #pragma unroll
    for (int k = 0; k < 16; ++k) acc[k] -= macc;

    // cross-j reduce via LDS transpose (Us reusable after barrier)
    __syncthreads();
    #pragma unroll
    for (int c = 0; c < 4; ++c)
        *(float4*)&Us[j16 * 256 + hc * 4 + 64 * c] =
            make_float4(acc[c*4+0], acc[c*4+1], acc[c*4+2], acc[c*4+3]);
    __syncthreads();
    float r = 0.f;
    #pragma unroll
    for (int q = 0; q < 16; ++q) r += Us[q * 256 + t];
    part[(size_t)blk * 256 + t] = r;
}

// K4: reduce 32 partials, apply lng_g / (4096 * lng_b), 256x128 GEMM + elu.
__global__ __launch_bounds__(128) void k_out(
    const float* __restrict__ part,
    const float* __restrict__ lgg, const float* __restrict__ lgb,
    const float* __restrict__ Wf,  const float* __restrict__ bfb,
    float* __restrict__ out) {
    int b = blockIdx.x;
    int f = threadIdx.x;  // 128
    __shared__ float sh[256];
    for (int h = f; h < 256; h += 128) {
        float s = 0.f;
        #pragma unroll
        for (int p = 0; p < 32; ++p) s += part[(size_t)(b * 32 + p) * 256 + h];
        sh[h] = fmaf(lgg[h], s, 4096.f * lgb[h]);
    }
    __syncthreads();
    float acc = bfb[f];
    for (int h = 0; h < 256; ++h)
        acc = fmaf(sh[h], Wf[h * 128 + f], acc);
    float r = acc > 0.f ? acc : __expf(acc) - 1.f;
    out[b * 128 + f] = r;
}

extern "C" void kernel_launch(void* const* d_in, const int* in_sizes, int n_in,
                              void* d_out, int out_size, void* d_ws, size_t ws_size,
                              hipStream_t stream) {
    const float* xa  = (const float*)d_in[0];
    const float* xb  = (const float*)d_in[1];
    const float* Wa  = (const float*)d_in[2];
    const float* ba  = (const float*)d_in[3];
    const float* Wb  = (const float*)d_in[4];
    const float* bb  = (const float*)d_in[5];
    const float* g0  = (const float*)d_in[6];
    const float* b0  = (const float*)d_in[7];
    const float* Wg  = (const float*)d_in[8];
    const float* bg  = (const float*)d_in[9];
    const float* lgg = (const float*)d_in[10];
    const float* lgb = (const float*)d_in[11];
    const float* Wf  = (const float*)d_in[12];
    const float* bfb = (const float*)d_in[13];
    float* out = (float*)d_out;

    float* ws   = (float*)d_ws;
    float* abar = ws + OFF_ABAR;
    float* U    = ws + OFF_U;
    float* V    = ws + OFF_V;
    float* part = ws + OFF_PART;

    k_embed_ln0<<<128, 256, 0, stream>>>(xa, xb, Wa, ba, Wb, bb, g0, b0, abar);
    k_uv<<<512, 256, 0, stream>>>(abar, Wg, bg, U, V);
    k_pair<<<4096, 256, 0, stream>>>(U, V, part);
    k_out<<<128, 128, 0, stream>>>(part, lgg, lgb, Wf, bfb, out);
}

// Round 13
// 151.461 us; speedup vs baseline: 1.1754x; 1.0232x over previous
//
#include <hip/hip_runtime.h>
#include <hip/hip_bf16.h>

#define EPS 1e-5f

// ---- workspace layout (float offsets) ----
#define OFF_ABAR 0          // 128*64*72   = 589824 floats
#define OFF_U    589824     // 128*64*256  = 2097152
#define OFF_V    2686976    // 2097152
#define OFF_PART 4784128    // 4096*256    = 1048576 -> total 5832704 fl = 23.3 MB

__device__ __forceinline__ float elu(float z) {
    return z > 0.f ? z : __expf(z) - 1.f;
}

// K1: fused split-embedding + LayerNorm over (N,E) per batch.
__global__ __launch_bounds__(256) void k_embed_ln0(
    const float* __restrict__ xa, const float* __restrict__ xb,
    const float* __restrict__ Wa, const float* __restrict__ ba,
    const float* __restrict__ Wb, const float* __restrict__ bb,
    const float* __restrict__ g0, const float* __restrict__ b0,
    float* __restrict__ abar) {
    int b = blockIdx.x;
    int tid = threadIdx.x;
    float vals[18];
    float s1 = 0.f, s2 = 0.f;
    for (int m = 0; m < 18; ++m) {
        int k = tid + 256 * m;
        int e = k % 72;
        int n = k / 72;
        float acc;
        if (n < 32) {
            acc = ba[e];
            const float* x = xa + (b * 32 + n) * 23;
            #pragma unroll
            for (int d = 0; d < 23; ++d) acc = fmaf(x[d], Wa[d * 72 + e], acc);
        } else {
            acc = bb[e];
            const float* x = xb + (b * 32 + (n - 32)) * 13;
            #pragma unroll
            for (int d = 0; d < 13; ++d) acc = fmaf(x[d], Wb[d * 72 + e], acc);
        }
        vals[m] = acc;
        s1 += acc;
        s2 = fmaf(acc, acc, s2);
    }
    #pragma unroll
    for (int off = 32; off >= 1; off >>= 1) {
        s1 += __shfl_xor(s1, off, 64);
        s2 += __shfl_xor(s2, off, 64);
    }
    __shared__ float r1[4], r2[4];
    int w = tid >> 6;
    if ((tid & 63) == 0) { r1[w] = s1; r2[w] = s2; }
    __syncthreads();
    float t1 = r1[0] + r1[1] + r1[2] + r1[3];
    float t2 = r2[0] + r2[1] + r2[2] + r2[3];
    float mean = t1 * (1.f / 4608.f);
    float var  = fmaf(-mean, mean, t2 * (1.f / 4608.f));
    float rsq  = rsqrtf(var + EPS);
    float* ab = abar + b * 4608;
    for (int m = 0; m < 18; ++m) {
        int k = tid + 256 * m;
        ab[k] = fmaf((vals[m] - mean) * rsq, g0[k], b0[k]);
    }
}

// K2: U = abar @ Wg[0:72,:] (+ b_g folded in), V = abar @ Wg[72:144,:].
// grid = 512 (128 b × 4 n-quarters), block = 256.
__global__ __launch_bounds__(256) void k_uv(
    const float* __restrict__ abar, const float* __restrict__ Wg,
    const float* __restrict__ bg,
    float* __restrict__ U, float* __restrict__ V) {
    int blk = blockIdx.x;            // 512 blocks
    int b = blk >> 2;
    int q = blk & 3;                 // n-range [q*16, q*16+16)
    int h = threadIdx.x;
    __shared__ float sa[72 * 16];    // [e][n], 4.5 KB
    const float* src = abar + (b * 64 + q * 16) * 72;
    for (int k = threadIdx.x; k < 72 * 16; k += 256) {
        int e = k >> 4, n = k & 15;
        sa[k] = src[n * 72 + e];
    }
    __syncthreads();
    float u[16], v[16];
    #pragma unroll
    for (int n = 0; n < 16; ++n) { u[n] = 0.f; v[n] = 0.f; }
    for (int e = 0; e < 72; ++e) {
        float wu = Wg[e * 256 + h];
        float wv = Wg[(72 + e) * 256 + h];
        const float4* sp = (const float4*)&sa[e * 16];
        #pragma unroll
        for (int n4 = 0; n4 < 4; ++n4) {
            float4 s4 = sp[n4];
            u[n4*4+0] = fmaf(s4.x, wu, u[n4*4+0]); v[n4*4+0] = fmaf(s4.x, wv, v[n4*4+0]);
            u[n4*4+1] = fmaf(s4.y, wu, u[n4*4+1]); v[n4*4+1] = fmaf(s4.y, wv, v[n4*4+1]);
            u[n4*4+2] = fmaf(s4.z, wu, u[n4*4+2]); v[n4*4+2] = fmaf(s4.z, wv, v[n4*4+2]);
            u[n4*4+3] = fmaf(s4.w, wu, u[n4*4+3]); v[n4*4+3] = fmaf(s4.w, wv, v[n4*4+3]);
        }
    }
    float bgh = bg[h];
    int base = (b * 64 + q * 16) * 256 + h;
    #pragma unroll
    for (int n = 0; n < 16; ++n) {
        U[base + n * 256] = u[n] + bgh;   // b_g folded into U
        V[base + n * 256] = v[n];
    }
}

// K3 v9 (FROZEN, R12): elu once, 16 h/thread, shfl stats reduce; 4096 blocks.
__global__ __launch_bounds__(256, 6) void k_pair(
    const float* __restrict__ U, const float* __restrict__ V,
    float* __restrict__ part) {
    int blk = blockIdx.x;
    int b  = blk >> 5;
    int iq = (blk >> 2) & 7;
    int jq = blk & 3;
    int t  = threadIdx.x;
    int j16 = t >> 4;             // 0..15
    int hc  = t & 15;             // 0..15

    __shared__ float Us[16 * 256];   // 16 KB: rows 0..7 = U tile; all = scratch

    // stage U[b, iq*8 .. +8) — coalesced float4 (2048 floats)
    const float* Ug = U + (size_t)(b * 64 + iq * 8) * 256;
    #pragma unroll
    for (int r = 0; r < 2; ++r) {
        int k = t * 4 + r * 1024;
        *(float4*)&Us[k] = *(const float4*)&Ug[k];
    }

    // V-slice into registers (16 consecutive lanes read dense rows)
    const float* Vrow = V + (size_t)(b * 64 + jq * 16 + j16) * 256;
    float v[16];
    #pragma unroll
    for (int c = 0; c < 4; ++c) {
        float4 v4 = *(const float4*)&Vrow[hc * 4 + 64 * c];
        v[c*4+0] = v4.x; v[c*4+1] = v4.y; v[c*4+2] = v4.z; v[c*4+3] = v4.w;
    }

    __syncthreads();

    float acc[16];
    #pragma unroll
    for (int k = 0; k < 16; ++k) acc[k] = 0.f;
    float macc = 0.f;

    for (int i = 0; i < 8; ++i) {
        const float* ur = &Us[i * 256];
        float e[16];
        float s1 = 0.f, s2 = 0.f;
        #pragma unroll
        for (int c = 0; c < 4; ++c) {
            float4 u4 = *(const float4*)&ur[hc * 4 + 64 * c];
            float e0 = elu(u4.x + v[c*4+0]);
            float e1 = elu(u4.y + v[c*4+1]);
            float e2 = elu(u4.z + v[c*4+2]);
            float e3 = elu(u4.w + v[c*4+3]);
            e[c*4+0] = e0; e[c*4+1] = e1; e[c*4+2] = e2; e[c*4+3] = e3;
            s1 += (e0 + e1) + (e2 + e3);
            s2 = fmaf(e0, e0, fmaf(e1, e1, fmaf(e2, e2, fmaf(e3, e3, s2))));
        }
        #pragma unroll
        for (int d = 1; d <= 8; d <<= 1) {
            s1 += __shfl_xor(s1, d, 64);
            s2 += __shfl_xor(s2, d, 64);
        }
        float mu  = s1 * (1.f / 256.f);
        float var = fmaf(-mu, mu, s2 * (1.f / 256.f));
        float rsq = rsqrtf(var + EPS);
        macc += mu * rsq;
        #pragma unroll
        for (int k = 0; k < 16; ++k) acc[k] = fmaf(e[k], rsq, acc[k]);
    }
    #pragma unroll
    for (int k = 0; k < 16; ++k) acc[k] -= macc;

    // cross-j reduce via LDS transpose (Us reusable after barrier)
    __syncthreads();
    #pragma unroll
    for (int c = 0; c < 4; ++c)
        *(float4*)&Us[j16 * 256 + hc * 4 + 64 * c] =
            make_float4(acc[c*4+0], acc[c*4+1], acc[c*4+2], acc[c*4+3]);
    __syncthreads();
    float r = 0.f;
    #pragma unroll
    for (int q = 0; q < 16; ++q) r += Us[q * 256 + t];
    part[(size_t)blk * 256 + t] = r;
}

// K4 v3: latency-parallel tail. block = 512 threads, grid = 128 b.
// Phase 1: 32-partial reduce with 512-way parallelism (2 thr/h × 16 p each).
// Phase 2: 256-h dot split 4 ways (f = t&127, hq = t>>7, 64 iters) + LDS sum.
__global__ __launch_bounds__(512) void k_out(
    const float* __restrict__ part,
    const float* __restrict__ lgg, const float* __restrict__ lgb,
    const float* __restrict__ Wf,  const float* __restrict__ bfb,
    float* __restrict__ out) {
    int b = blockIdx.x;
    int t = threadIdx.x;  // 512
    __shared__ float sh[256];
    __shared__ float ps[512];
    {
        int h = t & 255, pg = t >> 8;           // pg = 0/1
        float s = 0.f;
        #pragma unroll
        for (int p = 0; p < 16; ++p)
            s += part[(size_t)(b * 32 + pg * 16 + p) * 256 + h];
        ps[t] = s;
    }
    __syncthreads();
    if (t < 256) sh[t] = fmaf(lgg[t], ps[t] + ps[t + 256], 4096.f * lgb[t]);
    __syncthreads();
    {
        int f = t & 127, hq = t >> 7;           // hq = 0..3
        float acc = 0.f;
        #pragma unroll 8
        for (int h = hq * 64; h < hq * 64 + 64; ++h)
            acc = fmaf(sh[h], Wf[h * 128 + f], acc);
        ps[t] = acc;
    }
    __syncthreads();
    if (t < 128) {
        float r = ps[t] + ps[t + 128] + ps[t + 256] + ps[t + 384] + bfb[t];
        out[b * 128 + t] = r > 0.f ? r : __expf(r) - 1.f;
    }
}

extern "C" void kernel_launch(void* const* d_in, const int* in_sizes, int n_in,
                              void* d_out, int out_size, void* d_ws, size_t ws_size,
                              hipStream_t stream) {
    const float* xa  = (const float*)d_in[0];
    const float* xb  = (const float*)d_in[1];
    const float* Wa  = (const float*)d_in[2];
    const float* ba  = (const float*)d_in[3];
    const float* Wb  = (const float*)d_in[4];
    const float* bb  = (const float*)d_in[5];
    const float* g0  = (const float*)d_in[6];
    const float* b0  = (const float*)d_in[7];
    const float* Wg  = (const float*)d_in[8];
    const float* bg  = (const float*)d_in[9];
    const float* lgg = (const float*)d_in[10];
    const float* lgb = (const float*)d_in[11];
    const float* Wf  = (const float*)d_in[12];
    const float* bfb = (const float*)d_in[13];
    float* out = (float*)d_out;

    float* ws   = (float*)d_ws;
    float* abar = ws + OFF_ABAR;
    float* U    = ws + OFF_U;
    float* V    = ws + OFF_V;
    float* part = ws + OFF_PART;

    k_embed_ln0<<<128, 256, 0, stream>>>(xa, xb, Wa, ba, Wb, bb, g0, b0, abar);
    k_uv<<<512, 256, 0, stream>>>(abar, Wg, bg, U, V);
    k_pair<<<4096, 256, 0, stream>>>(U, V, part);
    k_out<<<128, 512, 0, stream>>>(part, lgg, lgb, Wf, bfb, out);
}

// Round 14
// 149.332 us; speedup vs baseline: 1.1922x; 1.0143x over previous
//
#include <hip/hip_runtime.h>
#include <hip/hip_bf16.h>

#define EPS 1e-5f

// ---- workspace layout (float offsets) ----
#define OFF_ABAR 0          // 128*64*72   = 589824 floats
#define OFF_U    589824     // 128*64*256  = 2097152
#define OFF_V    2686976    // 2097152
#define OFF_PART 4784128    // 4096*256    = 1048576 -> total 5832704 fl = 23.3 MB

__device__ __forceinline__ float elu(float z) {
    return z > 0.f ? z : __expf(z) - 1.f;
}

// K1 v2: fused split-embedding + LayerNorm, LDS-staged inputs/weights.
// One block per batch (LN needs the full 4608-elem reduce). All dot-product
// operands staged in LDS with coalesced global loads -> no per-MAC global
// latency. Thread owns 18 elems (k = tid + 256*m).
__global__ __launch_bounds__(256) void k_embed_ln0(
    const float* __restrict__ xa, const float* __restrict__ xb,
    const float* __restrict__ Wa, const float* __restrict__ ba,
    const float* __restrict__ Wb, const float* __restrict__ bb,
    const float* __restrict__ g0, const float* __restrict__ b0,
    float* __restrict__ abar) {
    int b = blockIdx.x;
    int tid = threadIdx.x;
    __shared__ float S[3888];        // 15.6 KB
    float* s_xa = S;                 // 736  = 32*23
    float* s_xb = S + 736;           // 416  = 32*13
    float* s_Wa = S + 1152;          // 1656 = 23*72
    float* s_Wb = S + 2808;          // 936  = 13*72
    float* s_ba = S + 3744;          // 72
    float* s_bb = S + 3816;          // 72
    for (int k = tid; k < 736;  k += 256) s_xa[k] = xa[b * 736 + k];
    for (int k = tid; k < 416;  k += 256) s_xb[k] = xb[b * 416 + k];
    for (int k = tid; k < 1656; k += 256) s_Wa[k] = Wa[k];
    for (int k = tid; k < 936;  k += 256) s_Wb[k] = Wb[k];
    if (tid < 72) { s_ba[tid] = ba[tid]; s_bb[tid] = bb[tid]; }
    __syncthreads();

    float vals[18];
    float s1 = 0.f, s2 = 0.f;
    #pragma unroll
    for (int m = 0; m < 18; ++m) {
        int k = tid + 256 * m;
        int e = k % 72;
        int n = k / 72;
        float acc;
        if (n < 32) {
            acc = s_ba[e];
            const float* x = s_xa + n * 23;
            #pragma unroll
            for (int d = 0; d < 23; ++d) acc = fmaf(x[d], s_Wa[d * 72 + e], acc);
        } else {
            acc = s_bb[e];
            const float* x = s_xb + (n - 32) * 13;
            #pragma unroll
            for (int d = 0; d < 13; ++d) acc = fmaf(x[d], s_Wb[d * 72 + e], acc);
        }
        vals[m] = acc;
        s1 += acc;
        s2 = fmaf(acc, acc, s2);
    }
    #pragma unroll
    for (int off = 32; off >= 1; off >>= 1) {
        s1 += __shfl_xor(s1, off, 64);
        s2 += __shfl_xor(s2, off, 64);
    }
    __shared__ float r1[4], r2[4];
    int w = tid >> 6;
    if ((tid & 63) == 0) { r1[w] = s1; r2[w] = s2; }
    __syncthreads();
    float t1 = r1[0] + r1[1] + r1[2] + r1[3];
    float t2 = r2[0] + r2[1] + r2[2] + r2[3];
    float mean = t1 * (1.f / 4608.f);
    float var  = fmaf(-mean, mean, t2 * (1.f / 4608.f));
    float rsq  = rsqrtf(var + EPS);
    float* ab = abar + b * 4608;
    #pragma unroll
    for (int m = 0; m < 18; ++m) {
        int k = tid + 256 * m;
        ab[k] = fmaf((vals[m] - mean) * rsq, g0[k], b0[k]);
    }
}

// K2 v3: U = abar @ Wg[0:72,:] (+ b_g), V = abar @ Wg[72:144,:].
// grid = 1024 (128 b × 8 n-octets), block = 256 (thread = one h column,
// 8 n accumulators). 4 blocks/CU × 4 waves = 16 waves/CU. e-loop unrolled
// ×6 so 12 independent Wg loads are in flight per batch of 96 FMAs.
__global__ __launch_bounds__(256) void k_uv(
    const float* __restrict__ abar, const float* __restrict__ Wg,
    const float* __restrict__ bg,
    float* __restrict__ U, float* __restrict__ V) {
    int blk = blockIdx.x;            // 1024 blocks
    int b = blk >> 3;
    int q = blk & 7;                 // n-range [q*8, q*8+8)
    int h = threadIdx.x;
    __shared__ float sa[72 * 8];     // [e][n], 2.25 KB
    const float* src = abar + (b * 64 + q * 8) * 72;
    for (int k = threadIdx.x; k < 72 * 8; k += 256) {
        int e = k >> 3, n = k & 7;
        sa[k] = src[n * 72 + e];
    }
    __syncthreads();
    float u[8], v[8];
    #pragma unroll
    for (int n = 0; n < 8; ++n) { u[n] = 0.f; v[n] = 0.f; }
    #pragma unroll 6
    for (int e = 0; e < 72; ++e) {
        float wu = Wg[e * 256 + h];
        float wv = Wg[(72 + e) * 256 + h];
        const float4* sp = (const float4*)&sa[e * 8];
        #pragma unroll
        for (int n4 = 0; n4 < 2; ++n4) {
            float4 s4 = sp[n4];
            u[n4*4+0] = fmaf(s4.x, wu, u[n4*4+0]); v[n4*4+0] = fmaf(s4.x, wv, v[n4*4+0]);
            u[n4*4+1] = fmaf(s4.y, wu, u[n4*4+1]); v[n4*4+1] = fmaf(s4.y, wv, v[n4*4+1]);
            u[n4*4+2] = fmaf(s4.z, wu, u[n4*4+2]); v[n4*4+2] = fmaf(s4.z, wv, v[n4*4+2]);
            u[n4*4+3] = fmaf(s4.w, wu, u[n4*4+3]); v[n4*4+3] = fmaf(s4.w, wv, v[n4*4+3]);
        }
    }
    float bgh = bg[h];
    int base = (b * 64 + q * 8) * 256 + h;
    #pragma unroll
    for (int n = 0; n < 8; ++n) {
        U[base + n * 256] = u[n] + bgh;   // b_g folded into U
        V[base + n * 256] = v[n];
    }
}

// K3 v9 (FROZEN, R12): elu once, 16 h/thread, shfl stats reduce; 4096 blocks.
__global__ __launch_bounds__(256, 6) void k_pair(
    const float* __restrict__ U, const float* __restrict__ V,
    float* __restrict__ part) {
    int blk = blockIdx.x;
    int b  = blk >> 5;
    int iq = (blk >> 2) & 7;
    int jq = blk & 3;
    int t  = threadIdx.x;
    int j16 = t >> 4;             // 0..15
    int hc  = t & 15;             // 0..15

    __shared__ float Us[16 * 256];   // 16 KB: rows 0..7 = U tile; all = scratch

    const float* Ug = U + (size_t)(b * 64 + iq * 8) * 256;
    #pragma unroll
    for (int r = 0; r < 2; ++r) {
        int k = t * 4 + r * 1024;
        *(float4*)&Us[k] = *(const float4*)&Ug[k];
    }

    const float* Vrow = V + (size_t)(b * 64 + jq * 16 + j16) * 256;
    float v[16];
    #pragma unroll
    for (int c = 0; c < 4; ++c) {
        float4 v4 = *(const float4*)&Vrow[hc * 4 + 64 * c];
        v[c*4+0] = v4.x; v[c*4+1] = v4.y; v[c*4+2] = v4.z; v[c*4+3] = v4.w;
    }

    __syncthreads();

    float acc[16];
    #pragma unroll
    for (int k = 0; k < 16; ++k) acc[k] = 0.f;
    float macc = 0.f;

    for (int i = 0; i < 8; ++i) {
        const float* ur = &Us[i * 256];
        float e[16];
        float s1 = 0.f, s2 = 0.f;
        #pragma unroll
        for (int c = 0; c < 4; ++c) {
            float4 u4 = *(const float4*)&ur[hc * 4 + 64 * c];
            float e0 = elu(u4.x + v[c*4+0]);
            float e1 = elu(u4.y + v[c*4+1]);
            float e2 = elu(u4.z + v[c*4+2]);
            float e3 = elu(u4.w + v[c*4+3]);
            e[c*4+0] = e0; e[c*4+1] = e1; e[c*4+2] = e2; e[c*4+3] = e3;
            s1 += (e0 + e1) + (e2 + e3);
            s2 = fmaf(e0, e0, fmaf(e1, e1, fmaf(e2, e2, fmaf(e3, e3, s2))));
        }
        #pragma unroll
        for (int d = 1; d <= 8; d <<= 1) {
            s1 += __shfl_xor(s1, d, 64);
            s2 += __shfl_xor(s2, d, 64);
        }
        float mu  = s1 * (1.f / 256.f);
        float var = fmaf(-mu, mu, s2 * (1.f / 256.f));
        float rsq = rsqrtf(var + EPS);
        macc += mu * rsq;
        #pragma unroll
        for (int k = 0; k < 16; ++k) acc[k] = fmaf(e[k], rsq, acc[k]);
    }
    #pragma unroll
    for (int k = 0; k < 16; ++k) acc[k] -= macc;

    __syncthreads();
    #pragma unroll
    for (int c = 0; c < 4; ++c)
        *(float4*)&Us[j16 * 256 + hc * 4 + 64 * c] =
            make_float4(acc[c*4+0], acc[c*4+1], acc[c*4+2], acc[c*4+3]);
    __syncthreads();
    float r = 0.f;
    #pragma unroll
    for (int q = 0; q < 16; ++q) r += Us[q * 256 + t];
    part[(size_t)blk * 256 + t] = r;
}

// K4 v3 (FROZEN, R13): latency-parallel tail. block = 512, grid = 128 b.
__global__ __launch_bounds__(512) void k_out(
    const float* __restrict__ part,
    const float* __restrict__ lgg, const float* __restrict__ lgb,
    const float* __restrict__ Wf,  const float* __restrict__ bfb,
    float* __restrict__ out) {
    int b = blockIdx.x;
    int t = threadIdx.x;  // 512
    __shared__ float sh[256];
    __shared__ float ps[512];
    {
        int h = t & 255, pg = t >> 8;           // pg = 0/1
        float s = 0.f;
        #pragma unroll
        for (int p = 0; p < 16; ++p)
            s += part[(size_t)(b * 32 + pg * 16 + p) * 256 + h];
        ps[t] = s;
    }
    __syncthreads();
    if (t < 256) sh[t] = fmaf(lgg[t], ps[t] + ps[t + 256], 4096.f * lgb[t]);
    __syncthreads();
    {
        int f = t & 127, hq = t >> 7;           // hq = 0..3
        float acc = 0.f;
        #pragma unroll 8
        for (int h = hq * 64; h < hq * 64 + 64; ++h)
            acc = fmaf(sh[h], Wf[h * 128 + f], acc);
        ps[t] = acc;
    }
    __syncthreads();
    if (t < 128) {
        float r = ps[t] + ps[t + 128] + ps[t + 256] + ps[t + 384] + bfb[t];
        out[b * 128 + t] = r > 0.f ? r : __expf(r) - 1.f;
    }
}

extern "C" void kernel_launch(void* const* d_in, const int* in_sizes, int n_in,
                              void* d_out, int out_size, void* d_ws, size_t ws_size,
                              hipStream_t stream) {
    const float* xa  = (const float*)d_in[0];
    const float* xb  = (const float*)d_in[1];
    const float* Wa  = (const float*)d_in[2];
    const float* ba  = (const float*)d_in[3];
    const float* Wb  = (const float*)d_in[4];
    const float* bb  = (const float*)d_in[5];
    const float* g0  = (const float*)d_in[6];
    const float* b0  = (const float*)d_in[7];
    const float* Wg  = (const float*)d_in[8];
    const float* bg  = (const float*)d_in[9];
    const float* lgg = (const float*)d_in[10];
    const float* lgb = (const float*)d_in[11];
    const float* Wf  = (const float*)d_in[12];
    const float* bfb = (const float*)d_in[13];
    float* out = (float*)d_out;

    float* ws   = (float*)d_ws;
    float* abar = ws + OFF_ABAR;
    float* U    = ws + OFF_U;
    float* V    = ws + OFF_V;
    float* part = ws + OFF_PART;

    k_embed_ln0<<<128, 256, 0, stream>>>(xa, xb, Wa, ba, Wb, bb, g0, b0, abar);
    k_uv<<<1024, 256, 0, stream>>>(abar, Wg, bg, U, V);
    k_pair<<<4096, 256, 0, stream>>>(U, V, part);
    k_out<<<128, 512, 0, stream>>>(part, lgg, lgb, Wf, bfb, out);
}

// Round 15
// 149.041 us; speedup vs baseline: 1.1945x; 1.0020x over previous
//
#include <hip/hip_runtime.h>
#include <hip/hip_bf16.h>

#define EPS 1e-5f

typedef float v2f __attribute__((ext_vector_type(2)));

// ---- workspace layout (float offsets) ----
#define OFF_ABAR 0          // 128*64*72   = 589824 floats
#define OFF_U    589824     // 128*64*256  = 2097152
#define OFF_V    2686976    // 2097152
#define OFF_PART 4784128    // 4096*256    = 1048576 -> total 5832704 fl = 23.3 MB

__device__ __forceinline__ float elu(float z) {
    return z > 0.f ? z : __expf(z) - 1.f;
}

// K1 v2 (FROZEN, R14): fused split-embedding + LayerNorm, LDS-staged operands.
__global__ __launch_bounds__(256) void k_embed_ln0(
    const float* __restrict__ xa, const float* __restrict__ xb,
    const float* __restrict__ Wa, const float* __restrict__ ba,
    const float* __restrict__ Wb, const float* __restrict__ bb,
    const float* __restrict__ g0, const float* __restrict__ b0,
    float* __restrict__ abar) {
    int b = blockIdx.x;
    int tid = threadIdx.x;
    __shared__ float S[3888];        // 15.6 KB
    float* s_xa = S;                 // 736  = 32*23
    float* s_xb = S + 736;           // 416  = 32*13
    float* s_Wa = S + 1152;          // 1656 = 23*72
    float* s_Wb = S + 2808;          // 936  = 13*72
    float* s_ba = S + 3744;          // 72
    float* s_bb = S + 3816;          // 72
    for (int k = tid; k < 736;  k += 256) s_xa[k] = xa[b * 736 + k];
    for (int k = tid; k < 416;  k += 256) s_xb[k] = xb[b * 416 + k];
    for (int k = tid; k < 1656; k += 256) s_Wa[k] = Wa[k];
    for (int k = tid; k < 936;  k += 256) s_Wb[k] = Wb[k];
    if (tid < 72) { s_ba[tid] = ba[tid]; s_bb[tid] = bb[tid]; }
    __syncthreads();

    float vals[18];
    float s1 = 0.f, s2 = 0.f;
    #pragma unroll
    for (int m = 0; m < 18; ++m) {
        int k = tid + 256 * m;
        int e = k % 72;
        int n = k / 72;
        float acc;
        if (n < 32) {
            acc = s_ba[e];
            const float* x = s_xa + n * 23;
            #pragma unroll
            for (int d = 0; d < 23; ++d) acc = fmaf(x[d], s_Wa[d * 72 + e], acc);
        } else {
            acc = s_bb[e];
            const float* x = s_xb + (n - 32) * 13;
            #pragma unroll
            for (int d = 0; d < 13; ++d) acc = fmaf(x[d], s_Wb[d * 72 + e], acc);
        }
        vals[m] = acc;
        s1 += acc;
        s2 = fmaf(acc, acc, s2);
    }
    #pragma unroll
    for (int off = 32; off >= 1; off >>= 1) {
        s1 += __shfl_xor(s1, off, 64);
        s2 += __shfl_xor(s2, off, 64);
    }
    __shared__ float r1[4], r2[4];
    int w = tid >> 6;
    if ((tid & 63) == 0) { r1[w] = s1; r2[w] = s2; }
    __syncthreads();
    float t1 = r1[0] + r1[1] + r1[2] + r1[3];
    float t2 = r2[0] + r2[1] + r2[2] + r2[3];
    float mean = t1 * (1.f / 4608.f);
    float var  = fmaf(-mean, mean, t2 * (1.f / 4608.f));
    float rsq  = rsqrtf(var + EPS);
    float* ab = abar + b * 4608;
    #pragma unroll
    for (int m = 0; m < 18; ++m) {
        int k = tid + 256 * m;
        ab[k] = fmaf((vals[m] - mean) * rsq, g0[k], b0[k]);
    }
}

// K2 v3 (FROZEN, R14): U/V GEMM, 1024 blocks, unroll-6 e-loop.
__global__ __launch_bounds__(256) void k_uv(
    const float* __restrict__ abar, const float* __restrict__ Wg,
    const float* __restrict__ bg,
    float* __restrict__ U, float* __restrict__ V) {
    int blk = blockIdx.x;            // 1024 blocks
    int b = blk >> 3;
    int q = blk & 7;                 // n-range [q*8, q*8+8)
    int h = threadIdx.x;
    __shared__ float sa[72 * 8];     // [e][n], 2.25 KB
    const float* src = abar + (b * 64 + q * 8) * 72;
    for (int k = threadIdx.x; k < 72 * 8; k += 256) {
        int e = k >> 3, n = k & 7;
        sa[k] = src[n * 72 + e];
    }
    __syncthreads();
    float u[8], v[8];
    #pragma unroll
    for (int n = 0; n < 8; ++n) { u[n] = 0.f; v[n] = 0.f; }
    #pragma unroll 6
    for (int e = 0; e < 72; ++e) {
        float wu = Wg[e * 256 + h];
        float wv = Wg[(72 + e) * 256 + h];
        const float4* sp = (const float4*)&sa[e * 8];
        #pragma unroll
        for (int n4 = 0; n4 < 2; ++n4) {
            float4 s4 = sp[n4];
            u[n4*4+0] = fmaf(s4.x, wu, u[n4*4+0]); v[n4*4+0] = fmaf(s4.x, wv, v[n4*4+0]);
            u[n4*4+1] = fmaf(s4.y, wu, u[n4*4+1]); v[n4*4+1] = fmaf(s4.y, wv, v[n4*4+1]);
            u[n4*4+2] = fmaf(s4.z, wu, u[n4*4+2]); v[n4*4+2] = fmaf(s4.z, wv, v[n4*4+2]);
            u[n4*4+3] = fmaf(s4.w, wu, u[n4*4+3]); v[n4*4+3] = fmaf(s4.w, wv, v[n4*4+3]);
        }
    }
    float bgh = bg[h];
    int base = (b * 64 + q * 8) * 256 + h;
    #pragma unroll
    for (int n = 0; n < 8; ++n) {
        U[base + n * 256] = u[n] + bgh;   // b_g folded into U
        V[base + n * 256] = v[n];
    }
}

// K3 v10: packed-f32 math. Same tiling as R12/R14 (16 h/thread, 4096 blocks,
// 8-i tiles) but inner arithmetic on ext_vector_type(2) floats so the backend
// can emit v_pk_add_f32 / v_pk_fma_f32 for the packable half of the per-elem
// mix (u+v, s1, s2, acc). elu (cmp/exp/sub/sel) stays scalar per component.
// No waves-per-EU cap: VGPR use ~40 naturally -> 8 blocks/CU residency.
__global__ __launch_bounds__(256) void k_pair(
    const float* __restrict__ U, const float* __restrict__ V,
    float* __restrict__ part) {
    int blk = blockIdx.x;
    int b  = blk >> 5;
    int iq = (blk >> 2) & 7;
    int jq = blk & 3;
    int t  = threadIdx.x;
    int j16 = t >> 4;             // 0..15
    int hc  = t & 15;             // 0..15

    __shared__ float Us[16 * 256];   // 16 KB: rows 0..7 = U tile; all = scratch

    const float* Ug = U + (size_t)(b * 64 + iq * 8) * 256;
    #pragma unroll
    for (int r = 0; r < 2; ++r) {
        int k = t * 4 + r * 1024;
        *(float4*)&Us[k] = *(const float4*)&Ug[k];
    }

    const float* Vrow = V + (size_t)(b * 64 + jq * 16 + j16) * 256;
    v2f v[8];
    #pragma unroll
    for (int c = 0; c < 4; ++c) {
        float4 v4 = *(const float4*)&Vrow[hc * 4 + 64 * c];
        v[2*c]   = (v2f){v4.x, v4.y};
        v[2*c+1] = (v2f){v4.z, v4.w};
    }

    __syncthreads();

    v2f acc[8];
    #pragma unroll
    for (int k = 0; k < 8; ++k) acc[k] = (v2f){0.f, 0.f};
    float macc = 0.f;

    for (int i = 0; i < 8; ++i) {
        const float* ur = &Us[i * 256];
        v2f e[8];
        v2f s1v = (v2f){0.f, 0.f};
        v2f s2v = (v2f){0.f, 0.f};
        #pragma unroll
        for (int c = 0; c < 4; ++c) {
            float4 u4 = *(const float4*)&ur[hc * 4 + 64 * c];
            v2f z0 = (v2f){u4.x, u4.y} + v[2*c];      // v_pk_add_f32
            v2f z1 = (v2f){u4.z, u4.w} + v[2*c+1];
            v2f e0, e1;
            e0.x = elu(z0.x); e0.y = elu(z0.y);       // scalar elu (exp pipe)
            e1.x = elu(z1.x); e1.y = elu(z1.y);
            e[2*c] = e0; e[2*c+1] = e1;
            s1v += e0 + e1;                            // v_pk_add_f32 ×2
            s2v = e0 * e0 + s2v;                       // v_pk_fma_f32
            s2v = e1 * e1 + s2v;
        }
        float s1 = s1v.x + s1v.y;
        float s2 = s2v.x + s2v.y;
        #pragma unroll
        for (int d = 1; d <= 8; d <<= 1) {
            s1 += __shfl_xor(s1, d, 64);
            s2 += __shfl_xor(s2, d, 64);
        }
        float mu  = s1 * (1.f / 256.f);
        float var = fmaf(-mu, mu, s2 * (1.f / 256.f));
        float rsq = rsqrtf(var + EPS);
        macc += mu * rsq;
        v2f r2 = (v2f){rsq, rsq};
        #pragma unroll
        for (int k = 0; k < 8; ++k) acc[k] = e[k] * r2 + acc[k];  // v_pk_fma_f32
    }
    v2f m2 = (v2f){macc, macc};
    #pragma unroll
    for (int k = 0; k < 8; ++k) acc[k] -= m2;

    // cross-j reduce via LDS transpose (Us reusable after barrier)
    __syncthreads();
    #pragma unroll
    for (int c = 0; c < 4; ++c)
        *(float4*)&Us[j16 * 256 + hc * 4 + 64 * c] =
            make_float4(acc[2*c].x, acc[2*c].y, acc[2*c+1].x, acc[2*c+1].y);
    __syncthreads();
    float r = 0.f;
    #pragma unroll
    for (int q = 0; q < 16; ++q) r += Us[q * 256 + t];
    part[(size_t)blk * 256 + t] = r;
}

// K4 v3 (FROZEN, R13): latency-parallel tail. block = 512, grid = 128 b.
__global__ __launch_bounds__(512) void k_out(
    const float* __restrict__ part,
    const float* __restrict__ lgg, const float* __restrict__ lgb,
    const float* __restrict__ Wf,  const float* __restrict__ bfb,
    float* __restrict__ out) {
    int b = blockIdx.x;
    int t = threadIdx.x;  // 512
    __shared__ float sh[256];
    __shared__ float ps[512];
    {
        int h = t & 255, pg = t >> 8;           // pg = 0/1
        float s = 0.f;
        #pragma unroll
        for (int p = 0; p < 16; ++p)
            s += part[(size_t)(b * 32 + pg * 16 + p) * 256 + h];
        ps[t] = s;
    }
    __syncthreads();
    if (t < 256) sh[t] = fmaf(lgg[t], ps[t] + ps[t + 256], 4096.f * lgb[t]);
    __syncthreads();
    {
        int f = t & 127, hq = t >> 7;           // hq = 0..3
        float acc = 0.f;
        #pragma unroll 8
        for (int h = hq * 64; h < hq * 64 + 64; ++h)
            acc = fmaf(sh[h], Wf[h * 128 + f], acc);
        ps[t] = acc;
    }
    __syncthreads();
    if (t < 128) {
        float r = ps[t] + ps[t + 128] + ps[t + 256] + ps[t + 384] + bfb[t];
        out[b * 128 + t] = r > 0.f ? r : __expf(r) - 1.f;
    }
}

extern "C" void kernel_launch(void* const* d_in, const int* in_sizes, int n_in,
                              void* d_out, int out_size, void* d_ws, size_t ws_size,
                              hipStream_t stream) {
    const float* xa  = (const float*)d_in[0];
    const float* xb  = (const float*)d_in[1];
    const float* Wa  = (const float*)d_in[2];
    const float* ba  = (const float*)d_in[3];
    const float* Wb  = (const float*)d_in[4];
    const float* bb  = (const float*)d_in[5];
    const float* g0  = (const float*)d_in[6];
    const float* b0  = (const float*)d_in[7];
    const float* Wg  = (const float*)d_in[8];
    const float* bg  = (const float*)d_in[9];
    const float* lgg = (const float*)d_in[10];
    const float* lgb = (const float*)d_in[11];
    const float* Wf  = (const float*)d_in[12];
    const float* bfb = (const float*)d_in[13];
    float* out = (float*)d_out;

    float* ws   = (float*)d_ws;
    float* abar = ws + OFF_ABAR;
    float* U    = ws + OFF_U;
    float* V    = ws + OFF_V;
    float* part = ws + OFF_PART;

    k_embed_ln0<<<128, 256, 0, stream>>>(xa, xb, Wa, ba, Wb, bb, g0, b0, abar);
    k_uv<<<1024, 256, 0, stream>>>(abar, Wg, bg, U, V);
    k_pair<<<4096, 256, 0, stream>>>(U, V, part);
    k_out<<<128, 512, 0, stream>>>(part, lgg, lgb, Wf, bfb, out);
}

// Round 16
// 144.209 us; speedup vs baseline: 1.2346x; 1.0335x over previous
//
#include <hip/hip_runtime.h>
#include <hip/hip_bf16.h>

#define EPS 1e-5f
#define LOG2E 1.44269504088896f
#define LN2   0.69314718055995f

typedef float v2f __attribute__((ext_vector_type(2)));

// ---- workspace layout (float offsets) ----
#define OFF_ABAR 0          // 128*64*72   = 589824 floats
#define OFF_U    589824     // 128*64*256  = 2097152
#define OFF_V    2686976    // 2097152
#define OFF_PART 4784128    // 4096*256    = 1048576 -> total 5832704 fl = 23.3 MB

__device__ __forceinline__ float elu(float z) {
    return z > 0.f ? z : __expf(z) - 1.f;
}

// K1 v2 (FROZEN, R14): fused split-embedding + LayerNorm, LDS-staged operands.
__global__ __launch_bounds__(256) void k_embed_ln0(
    const float* __restrict__ xa, const float* __restrict__ xb,
    const float* __restrict__ Wa, const float* __restrict__ ba,
    const float* __restrict__ Wb, const float* __restrict__ bb,
    const float* __restrict__ g0, const float* __restrict__ b0,
    float* __restrict__ abar) {
    int b = blockIdx.x;
    int tid = threadIdx.x;
    __shared__ float S[3888];        // 15.6 KB
    float* s_xa = S;                 // 736  = 32*23
    float* s_xb = S + 736;           // 416  = 32*13
    float* s_Wa = S + 1152;          // 1656 = 23*72
    float* s_Wb = S + 2808;          // 936  = 13*72
    float* s_ba = S + 3744;          // 72
    float* s_bb = S + 3816;          // 72
    for (int k = tid; k < 736;  k += 256) s_xa[k] = xa[b * 736 + k];
    for (int k = tid; k < 416;  k += 256) s_xb[k] = xb[b * 416 + k];
    for (int k = tid; k < 1656; k += 256) s_Wa[k] = Wa[k];
    for (int k = tid; k < 936;  k += 256) s_Wb[k] = Wb[k];
    if (tid < 72) { s_ba[tid] = ba[tid]; s_bb[tid] = bb[tid]; }
    __syncthreads();

    float vals[18];
    float s1 = 0.f, s2 = 0.f;
    #pragma unroll
    for (int m = 0; m < 18; ++m) {
        int k = tid + 256 * m;
        int e = k % 72;
        int n = k / 72;
        float acc;
        if (n < 32) {
            acc = s_ba[e];
            const float* x = s_xa + n * 23;
            #pragma unroll
            for (int d = 0; d < 23; ++d) acc = fmaf(x[d], s_Wa[d * 72 + e], acc);
        } else {
            acc = s_bb[e];
            const float* x = s_xb + (n - 32) * 13;
            #pragma unroll
            for (int d = 0; d < 13; ++d) acc = fmaf(x[d], s_Wb[d * 72 + e], acc);
        }
        vals[m] = acc;
        s1 += acc;
        s2 = fmaf(acc, acc, s2);
    }
    #pragma unroll
    for (int off = 32; off >= 1; off >>= 1) {
        s1 += __shfl_xor(s1, off, 64);
        s2 += __shfl_xor(s2, off, 64);
    }
    __shared__ float r1[4], r2[4];
    int w = tid >> 6;
    if ((tid & 63) == 0) { r1[w] = s1; r2[w] = s2; }
    __syncthreads();
    float t1 = r1[0] + r1[1] + r1[2] + r1[3];
    float t2 = r2[0] + r2[1] + r2[2] + r2[3];
    float mean = t1 * (1.f / 4608.f);
    float var  = fmaf(-mean, mean, t2 * (1.f / 4608.f));
    float rsq  = rsqrtf(var + EPS);
    float* ab = abar + b * 4608;
    #pragma unroll
    for (int m = 0; m < 18; ++m) {
        int k = tid + 256 * m;
        ab[k] = fmaf((vals[m] - mean) * rsq, g0[k], b0[k]);
    }
}

// K2 v3 (FROZEN, R14): U/V GEMM, 1024 blocks, unroll-6 e-loop.
__global__ __launch_bounds__(256) void k_uv(
    const float* __restrict__ abar, const float* __restrict__ Wg,
    const float* __restrict__ bg,
    float* __restrict__ U, float* __restrict__ V) {
    int blk = blockIdx.x;            // 1024 blocks
    int b = blk >> 3;
    int q = blk & 7;                 // n-range [q*8, q*8+8)
    int h = threadIdx.x;
    __shared__ float sa[72 * 8];     // [e][n], 2.25 KB
    const float* src = abar + (b * 64 + q * 8) * 72;
    for (int k = threadIdx.x; k < 72 * 8; k += 256) {
        int e = k >> 3, n = k & 7;
        sa[k] = src[n * 72 + e];
    }
    __syncthreads();
    float u[8], v[8];
    #pragma unroll
    for (int n = 0; n < 8; ++n) { u[n] = 0.f; v[n] = 0.f; }
    #pragma unroll 6
    for (int e = 0; e < 72; ++e) {
        float wu = Wg[e * 256 + h];
        float wv = Wg[(72 + e) * 256 + h];
        const float4* sp = (const float4*)&sa[e * 8];
        #pragma unroll
        for (int n4 = 0; n4 < 2; ++n4) {
            float4 s4 = sp[n4];
            u[n4*4+0] = fmaf(s4.x, wu, u[n4*4+0]); v[n4*4+0] = fmaf(s4.x, wv, v[n4*4+0]);
            u[n4*4+1] = fmaf(s4.y, wu, u[n4*4+1]); v[n4*4+1] = fmaf(s4.y, wv, v[n4*4+1]);
            u[n4*4+2] = fmaf(s4.z, wu, u[n4*4+2]); v[n4*4+2] = fmaf(s4.z, wv, v[n4*4+2]);
            u[n4*4+3] = fmaf(s4.w, wu, u[n4*4+3]); v[n4*4+3] = fmaf(s4.w, wv, v[n4*4+3]);
        }
    }
    float bgh = bg[h];
    int base = (b * 64 + q * 8) * 256 + h;
    #pragma unroll
    for (int n = 0; n < 8; ++n) {
        U[base + n * 256] = u[n] + bgh;   // b_g folded into U
        V[base + n * 256] = v[n];
    }
}

// K3 v11: packed-f32 + exp-fold + shuffle-ILP.
// Same tiling as v10 (16 h/thread, 4096 blocks, 8-i tiles). Changes:
//  (a) zl = z*log2e via pk_mul feeds v_exp directly (2^zl == exp(z)) —
//      removes the per-scalar mul inside __expf; select uses zl's sign.
//  (b) i-loop unrolled ×2 so two independent s1/s2 butterfly chains
//      interleave (halves exposed cross-lane latency at ~4.5 waves/SIMD).
__global__ __launch_bounds__(256) void k_pair(
    const float* __restrict__ U, const float* __restrict__ V,
    float* __restrict__ part) {
    int blk = blockIdx.x;
    int b  = blk >> 5;
    int iq = (blk >> 2) & 7;
    int jq = blk & 3;
    int t  = threadIdx.x;
    int j16 = t >> 4;             // 0..15
    int hc  = t & 15;             // 0..15

    __shared__ float Us[16 * 256];   // 16 KB: rows 0..7 = U tile; all = scratch

    const float* Ug = U + (size_t)(b * 64 + iq * 8) * 256;
    #pragma unroll
    for (int r = 0; r < 2; ++r) {
        int k = t * 4 + r * 1024;
        *(float4*)&Us[k] = *(const float4*)&Ug[k];
    }

    const float* Vrow = V + (size_t)(b * 64 + jq * 16 + j16) * 256;
    v2f v[8];
    #pragma unroll
    for (int c = 0; c < 4; ++c) {
        float4 v4 = *(const float4*)&Vrow[hc * 4 + 64 * c];
        v[2*c]   = (v2f){v4.x, v4.y};
        v[2*c+1] = (v2f){v4.z, v4.w};
    }

    __syncthreads();

    v2f acc[8];
    #pragma unroll
    for (int k = 0; k < 8; ++k) acc[k] = (v2f){0.f, 0.f};
    float macc = 0.f;

    #pragma unroll 2
    for (int i = 0; i < 8; ++i) {
        const float* ur = &Us[i * 256];
        v2f e[8];
        v2f s1v = (v2f){0.f, 0.f};
        v2f s2v = (v2f){0.f, 0.f};
        #pragma unroll
        for (int c = 0; c < 8; ++c) {
            float2 u2 = *(const float2*)&ur[hc * 4 + 32 * c + (c & 1) * 0];
            // layout: c enumerates the 8 v2-chunks; address = hc*4 + 64*(c>>1) + 2*(c&1)... 
            // keep original grouping instead:
            (void)u2;
        }
        #pragma unroll
        for (int c = 0; c < 4; ++c) {
            float4 u4 = *(const float4*)&ur[hc * 4 + 64 * c];
            v2f z0 = (v2f){u4.x, u4.y} + v[2*c];      // v_pk_add_f32
            v2f z1 = (v2f){u4.z, u4.w} + v[2*c+1];
            v2f zl0 = z0 * (v2f){LOG2E, LOG2E};        // v_pk_mul_f32
            v2f zl1 = z1 * (v2f){LOG2E, LOG2E};
            v2f e0, e1;
            e0.x = zl0.x > 0.f ? z0.x : __builtin_amdgcn_exp2f(zl0.x) - 1.f;
            e0.y = zl0.y > 0.f ? z0.y : __builtin_amdgcn_exp2f(zl0.y) - 1.f;
            e1.x = zl1.x > 0.f ? z1.x : __builtin_amdgcn_exp2f(zl1.x) - 1.f;
            e1.y = zl1.y > 0.f ? z1.y : __builtin_amdgcn_exp2f(zl1.y) - 1.f;
            e[2*c] = e0; e[2*c+1] = e1;
            s1v += e0 + e1;                            // v_pk_add_f32 ×2
            s2v = e0 * e0 + s2v;                       // v_pk_fma_f32
            s2v = e1 * e1 + s2v;
        }
        float s1 = s1v.x + s1v.y;
        float s2 = s2v.x + s2v.y;
        #pragma unroll
        for (int d = 1; d <= 8; d <<= 1) {
            s1 += __shfl_xor(s1, d, 64);
            s2 += __shfl_xor(s2, d, 64);
        }
        float mu  = s1 * (1.f / 256.f);
        float var = fmaf(-mu, mu, s2 * (1.f / 256.f));
        float rsq = rsqrtf(var + EPS);
        macc += mu * rsq;
        v2f r2 = (v2f){rsq, rsq};
        #pragma unroll
        for (int k = 0; k < 8; ++k) acc[k] = e[k] * r2 + acc[k];  // v_pk_fma_f32
    }
    v2f m2 = (v2f){macc, macc};
    #pragma unroll
    for (int k = 0; k < 8; ++k) acc[k] -= m2;

    // cross-j reduce via LDS transpose (Us reusable after barrier)
    __syncthreads();
    #pragma unroll
    for (int c = 0; c < 4; ++c)
        *(float4*)&Us[j16 * 256 + hc * 4 + 64 * c] =
            make_float4(acc[2*c].x, acc[2*c].y, acc[2*c+1].x, acc[2*c+1].y);
    __syncthreads();
    float r = 0.f;
    #pragma unroll
    for (int q = 0; q < 16; ++q) r += Us[q * 256 + t];
    part[(size_t)blk * 256 + t] = r;
}

// K4 v3 (FROZEN, R13): latency-parallel tail. block = 512, grid = 128 b.
__global__ __launch_bounds__(512) void k_out(
    const float* __restrict__ part,
    const float* __restrict__ lgg, const float* __restrict__ lgb,
    const float* __restrict__ Wf,  const float* __restrict__ bfb,
    float* __restrict__ out) {
    int b = blockIdx.x;
    int t = threadIdx.x;  // 512
    __shared__ float sh[256];
    __shared__ float ps[512];
    {
        int h = t & 255, pg = t >> 8;           // pg = 0/1
        float s = 0.f;
        #pragma unroll
        for (int p = 0; p < 16; ++p)
            s += part[(size_t)(b * 32 + pg * 16 + p) * 256 + h];
        ps[t] = s;
    }
    __syncthreads();
    if (t < 256) sh[t] = fmaf(lgg[t], ps[t] + ps[t + 256], 4096.f * lgb[t]);
    __syncthreads();
    {
        int f = t & 127, hq = t >> 7;           // hq = 0..3
        float acc = 0.f;
        #pragma unroll 8
        for (int h = hq * 64; h < hq * 64 + 64; ++h)
            acc = fmaf(sh[h], Wf[h * 128 + f], acc);
        ps[t] = acc;
    }
    __syncthreads();
    if (t < 128) {
        float r = ps[t] + ps[t + 128] + ps[t + 256] + ps[t + 384] + bfb[t];
        out[b * 128 + t] = r > 0.f ? r : __expf(r) - 1.f;
    }
}

extern "C" void kernel_launch(void* const* d_in, const int* in_sizes, int n_in,
                              void* d_out, int out_size, void* d_ws, size_t ws_size,
                              hipStream_t stream) {
    const float* xa  = (const float*)d_in[0];
    const float* xb  = (const float*)d_in[1];
    const float* Wa  = (const float*)d_in[2];
    const float* ba  = (const float*)d_in[3];
    const float* Wb  = (const float*)d_in[4];
    const float* bb  = (const float*)d_in[5];
    const float* g0  = (const float*)d_in[6];
    const float* b0  = (const float*)d_in[7];
    const float* Wg  = (const float*)d_in[8];
    const float* bg  = (const float*)d_in[9];
    const float* lgg = (const float*)d_in[10];
    const float* lgb = (const float*)d_in[11];
    const float* Wf  = (const float*)d_in[12];
    const float* bfb = (const float*)d_in[13];
    float* out = (float*)d_out;

    float* ws   = (float*)d_ws;
    float* abar = ws + OFF_ABAR;
    float* U    = ws + OFF_U;
    float* V    = ws + OFF_V;
    float* part = ws + OFF_PART;

    k_embed_ln0<<<128, 256, 0, stream>>>(xa, xb, Wa, ba, Wb, bb, g0, b0, abar);
    k_uv<<<1024, 256, 0, stream>>>(abar, Wg, bg, U, V);
    k_pair<<<4096, 256, 0, stream>>>(U, V, part);
    k_out<<<128, 512, 0, stream>>>(part, lgg, lgb, Wf, bfb, out);
}